// Round 2
// baseline (1291.142 us; speedup 1.0000x reference)
//
#include <hip/hip_runtime.h>
#include <hip/hip_bf16.h>

// ---------------------------------------------------------------------------
// GNN forward on MI355X, round 2.
//  * activations stored as SPLIT bf16 hi/lo planes in LDS (split once in
//    epilogue, not at every A-load) -> VALU off the critical path
//  * 64 rows/block, 64 KB LDS -> 2 blocks/CU, 2 waves/SIMD (TLP overlap)
//  * XOR swizzle (cg ^= row&7) -> conflict-free ds_read_b128 (T2)
//  * MFMA operands swapped (W first): lane holds 4 consecutive cols of one
//    row -> b64 epilogue writes
//  * wave grid 2x2 (32 rows x 64 cols per wave), W prefetched across layers
// ---------------------------------------------------------------------------

#define H        128
#define FEAT     32
#define M_NODES  32768
#define L_LAYERS 16
#define MU_      (M_NODES / 2)
#define N_TOTAL  (M_NODES * L_LAYERS)

typedef __bf16 bf16x8 __attribute__((ext_vector_type(8)));
typedef __bf16 bf16x4 __attribute__((ext_vector_type(4)));
typedef float  f32x4  __attribute__((ext_vector_type(4)));

// frag-pair slots in d_ws. One frag-pair = 2 KB = 1024 __bf16 (512 hi, 512 lo).
// frag-pair(ct,kt) lane l holds W[ct*16+(l&15)][kt*32+(l>>4)*8 + j], j=0..7.
#define SLOT_MPU(l) ((l) * 32)        // 5 layers, K=128 (8ct x 4kt)
#define SLOT_MPB0   160               // K=256 (8ct x 8kt)
#define SLOT_MPB(l) (224 + (l) * 32)  // 4 layers, K=128
#define SLOT_NE0    352               // K=256
#define SLOT_NE(l)  (416 + (l) * 32)  // 4 layers, K=128
#define TOTAL_FP    544

// LDS plane layout: [64 rows][128 cols] bf16, col-group (8 elems = 16 B)
// XOR-swizzled by row for bank-conflict-free row-wise b128 reads.
#define CG_SWZ(row, cg) ((cg) ^ ((row) & 7))

// ---------------------------------------------------------------------------
__global__ void prep_kernel(__bf16* __restrict__ frags,
                            const float* __restrict__ mpu_w,
                            const float* __restrict__ mpb0_w,
                            const float* __restrict__ mpb_w,
                            const float* __restrict__ ne0_w,
                            const float* __restrict__ ne_w) {
  int fp = blockIdx.x * 4 + (threadIdx.x >> 6);
  if (fp >= TOTAL_FP) return;
  int lane = threadIdx.x & 63;
  const float* src; int K; int idx;
  if (fp < 160)      { src = mpu_w + (fp >> 5) * H * H;         K = H;     idx = fp & 31; }
  else if (fp < 224) { src = mpb0_w;                            K = 2 * H; idx = fp - 160; }
  else if (fp < 352) { src = mpb_w + ((fp - 224) >> 5) * H * H; K = H;     idx = (fp - 224) & 31; }
  else if (fp < 416) { src = ne0_w;                             K = 2 * H; idx = fp - 352; }
  else               { src = ne_w + ((fp - 416) >> 5) * H * H;  K = H;     idx = (fp - 416) & 31; }
  int KT = K >> 5;
  int ct = idx / KT, kt = idx - ct * KT;
  int col = ct * 16 + (lane & 15);
  int k0  = kt * 32 + (lane >> 4) * 8;
  __bf16* dhi = frags + ((size_t)fp << 10) + lane * 8;
#pragma unroll
  for (int j = 0; j < 8; ++j) {
    float x  = src[col * K + k0 + j];
    __bf16 h = (__bf16)x;
    dhi[j]       = h;
    dhi[512 + j] = (__bf16)(x - (float)h);
  }
}

// ---------------------------------------------------------------------------
__global__ void embed_kernel(float* __restrict__ E,
                             const float* __restrict__ feats,
                             const float* __restrict__ emb_w,
                             const float* __restrict__ emb_b) {
  __shared__ float fl[64][36];
  int tid = threadIdx.x;
  size_t rbase = (size_t)blockIdx.x * 64;
  {
    int idx = tid;
#pragma unroll
    for (int rep = 0; rep < 2; ++rep, idx += 256) {
      int r = idx >> 3, c4 = idx & 7;
      *(f32x4*)&fl[r][c4 * 4] = *(const f32x4*)(feats + (rbase + r) * FEAT + c4 * 4);
    }
  }
  __syncthreads();
  int o = tid & 127, rh = tid >> 7;
  float w[32];
#pragma unroll
  for (int i = 0; i < 8; ++i) {
    f32x4 v = *(const f32x4*)(emb_w + o * FEAT + i * 4);
    w[i * 4 + 0] = v[0]; w[i * 4 + 1] = v[1]; w[i * 4 + 2] = v[2]; w[i * 4 + 3] = v[3];
  }
  float b = emb_b[o];
  for (int i = 0; i < 32; ++i) {
    int r = rh * 32 + i;
    float acc = b;
#pragma unroll
    for (int k4 = 0; k4 < 8; ++k4) {
      f32x4 f = *(const f32x4*)&fl[r][k4 * 4];
      acc += f[0] * w[k4 * 4] + f[1] * w[k4 * 4 + 1] + f[2] * w[k4 * 4 + 2] + f[3] * w[k4 * 4 + 3];
    }
    E[(rbase + r) * H + o] = fmaxf(acc, 0.f);
  }
}

// ---------------------------------------------------------------------------
struct WF { bf16x8 h[4][4]; bf16x8 l[4][4]; };  // [ct2][kt] hi/lo, 128 VGPR

__device__ __forceinline__ void load_w(WF& w, const __bf16* __restrict__ frags,
                                       int slot, int KT, int ktoff, int wc, int lane) {
#pragma unroll
  for (int c = 0; c < 4; ++c)
#pragma unroll
    for (int kt = 0; kt < 4; ++kt) {
      const __bf16* fb =
          frags + (((size_t)(slot + (wc * 4 + c) * KT + ktoff + kt)) << 10) + lane * 8;
      w.h[c][kt] = *(const bf16x8*)fb;
      w.l[c][kt] = *(const bf16x8*)(fb + 512);
    }
}

__device__ __forceinline__ void zero_acc(f32x4 (&acc)[2][4]) {
  f32x4 z = {0.f, 0.f, 0.f, 0.f};
#pragma unroll
  for (int i = 0; i < 2; ++i)
#pragma unroll
    for (int c = 0; c < 4; ++c) acc[i][c] = z;
}

// acc += split3( act[32 rows of wr] @ W^T ), K=128 pass from hi/lo planes.
// MFMA operand order: W first, act second -> D[lane&15 = act row][(lane>>4)*4+reg = w col]
__device__ __forceinline__ void gemm_mfma(f32x4 (&acc)[2][4], const WF& w,
                                          const __bf16* Ph, const __bf16* Pl,
                                          int wr, int lane) {
  int r16 = lane & 15, g = lane >> 4;
  bf16x8 ah[2][4], al[2][4];
#pragma unroll
  for (int i = 0; i < 2; ++i) {
    int row = wr * 32 + i * 16 + r16;
#pragma unroll
    for (int kt = 0; kt < 4; ++kt) {
      int off = row * H + CG_SWZ(row, kt * 4 + g) * 8;
      ah[i][kt] = *(const bf16x8*)(Ph + off);
      al[i][kt] = *(const bf16x8*)(Pl + off);
    }
  }
  // term 1: w_hi x a_hi   (same-acc revisit distance = 8)
#pragma unroll
  for (int kt = 0; kt < 4; ++kt)
#pragma unroll
    for (int i = 0; i < 2; ++i)
#pragma unroll
      for (int c = 0; c < 4; ++c)
        acc[i][c] = __builtin_amdgcn_mfma_f32_16x16x32_bf16(w.h[c][kt], ah[i][kt], acc[i][c], 0, 0, 0);
  // term 2: w_lo x a_hi
#pragma unroll
  for (int kt = 0; kt < 4; ++kt)
#pragma unroll
    for (int i = 0; i < 2; ++i)
#pragma unroll
      for (int c = 0; c < 4; ++c)
        acc[i][c] = __builtin_amdgcn_mfma_f32_16x16x32_bf16(w.l[c][kt], ah[i][kt], acc[i][c], 0, 0, 0);
  // term 3: w_hi x a_lo
#pragma unroll
  for (int kt = 0; kt < 4; ++kt)
#pragma unroll
    for (int i = 0; i < 2; ++i)
#pragma unroll
      for (int c = 0; c < 4; ++c)
        acc[i][c] = __builtin_amdgcn_mfma_f32_16x16x32_bf16(w.h[c][kt], al[i][kt], acc[i][c], 0, 0, 0);
}

// mode 0: C = relu(acc+b)
// mode 1: old = C; C = relu(acc+b); S = C + old
// mode 2: global fp32 store only
__device__ __forceinline__ void epilogue(const f32x4 (&acc)[2][4], const float* __restrict__ bias,
                                         int mode, float* __restrict__ eout, int wr, int wc,
                                         int lane, __bf16* Ch, __bf16* Cl, __bf16* Sh, __bf16* Sl) {
  int r16 = lane & 15, g = lane >> 4;
#pragma unroll
  for (int c = 0; c < 4; ++c) {
    int c0 = wc * 64 + c * 16 + g * 4;
    f32x4 bv = *(const f32x4*)(bias + c0);
#pragma unroll
    for (int i = 0; i < 2; ++i) {
      int row = wr * 32 + i * 16 + r16;
      f32x4 v;
#pragma unroll
      for (int j = 0; j < 4; ++j) v[j] = fmaxf(acc[i][c][j] + bv[j], 0.f);
      if (mode == 2) {
        *(f32x4*)(eout + (size_t)row * H + c0) = v;
      } else {
        int off = row * H + CG_SWZ(row, c0 >> 3) * 8 + (c0 & 7);
        if (mode == 1) {
          bf16x4 oh = *(bf16x4*)(Ch + off), ol = *(bf16x4*)(Cl + off);
          bf16x4 sh, sl;
#pragma unroll
          for (int j = 0; j < 4; ++j) {
            float sv = v[j] + (float)oh[j] + (float)ol[j];
            __bf16 t = (__bf16)sv;
            sh[j] = t; sl[j] = (__bf16)(sv - (float)t);
          }
          *(bf16x4*)(Sh + off) = sh; *(bf16x4*)(Sl + off) = sl;
        }
        bf16x4 h, l;
#pragma unroll
        for (int j = 0; j < 4; ++j) {
          __bf16 t = (__bf16)v[j];
          h[j] = t; l[j] = (__bf16)(v[j] - (float)t);
        }
        *(bf16x4*)(Ch + off) = h; *(bf16x4*)(Cl + off) = l;
      }
    }
  }
}

// thread covers floats [q*32, q*32+32) of `row`; splits into hi/lo planes.
__device__ __forceinline__ void stage_row(const float* __restrict__ src, __bf16* Ph, __bf16* Pl,
                                          int row, int q) {
#pragma unroll
  for (int i = 0; i < 4; ++i) {
    int cg = q * 4 + i;
    f32x4 f0 = *(const f32x4*)(src + cg * 8);
    f32x4 f1 = *(const f32x4*)(src + cg * 8 + 4);
    bf16x8 h, l;
#pragma unroll
    for (int j = 0; j < 4; ++j) {
      __bf16 t = (__bf16)f0[j]; h[j] = t; l[j] = (__bf16)(f0[j] - (float)t);
    }
#pragma unroll
    for (int j = 0; j < 4; ++j) {
      __bf16 t = (__bf16)f1[j]; h[4 + j] = t; l[4 + j] = (__bf16)(f1[j] - (float)t);
    }
    int off = row * H + CG_SWZ(row, cg) * 8;
    *(bf16x8*)(Ph + off) = h;
    *(bf16x8*)(Pl + off) = l;
  }
}

// ---------------------------------------------------------------------------
__global__ __launch_bounds__(256, 2) void phase_kernel(
    float* __restrict__ E, const int* __restrict__ parents, const __bf16* __restrict__ frags,
    const float* __restrict__ mpu_b, const float* __restrict__ mpb0_b,
    const float* __restrict__ mpb_b, const float* __restrict__ ne0_b,
    const float* __restrict__ ne_b, int s) {
  __shared__ __bf16 Ch[64 * H], Cl[64 * H], Sh[64 * H], Sl[64 * H];
  int t = blockIdx.x;
  bool un = t < (MU_ / 64);
  int row0 = t * 64;
  int tid = threadIdx.x;
  int lane = tid & 63, wave = tid >> 6;
  int wr = wave >> 1, wc = wave & 1;
  int srow = tid >> 2, q = tid & 3;
  int gr = s + row0 + srow;

  f32x4 acc[2][4];
  WF w1, w2;

  // ---- stage gathered message rows (split to planes) ----
  if (un) {
    stage_row(E + (size_t)parents[2 * gr] * H, Ch, Cl, srow, q);
    load_w(w1, frags, SLOT_MPU(0), 4, 0, wc, lane);
    __syncthreads();
    // L0: in C -> mode0 (C = a0)
    zero_acc(acc); gemm_mfma(acc, w1, Ch, Cl, wr, lane); __syncthreads();
    load_w(w1, frags, SLOT_MPU(1), 4, 0, wc, lane);
    epilogue(acc, mpu_b, 0, nullptr, wr, wc, lane, Ch, Cl, Sh, Sl); __syncthreads();
    // L1: in C -> mode1 (C=a1, S=a0+a1)
    zero_acc(acc); gemm_mfma(acc, w1, Ch, Cl, wr, lane); __syncthreads();
    load_w(w1, frags, SLOT_MPU(2), 4, 0, wc, lane);
    epilogue(acc, mpu_b + H, 1, nullptr, wr, wc, lane, Ch, Cl, Sh, Sl); __syncthreads();
    // L2: in S -> mode1
    zero_acc(acc); gemm_mfma(acc, w1, Sh, Sl, wr, lane); __syncthreads();
    load_w(w1, frags, SLOT_MPU(3), 4, 0, wc, lane);
    epilogue(acc, mpu_b + 2 * H, 1, nullptr, wr, wc, lane, Ch, Cl, Sh, Sl); __syncthreads();
    // L3: in S -> mode1
    zero_acc(acc); gemm_mfma(acc, w1, Sh, Sl, wr, lane); __syncthreads();
    load_w(w1, frags, SLOT_MPU(4), 4, 0, wc, lane);
    epilogue(acc, mpu_b + 3 * H, 1, nullptr, wr, wc, lane, Ch, Cl, Sh, Sl); __syncthreads();
    // L4: in S -> mode0 (C = redux result)
    zero_acc(acc); gemm_mfma(acc, w1, Sh, Sl, wr, lane); __syncthreads();
    load_w(w1, frags, SLOT_NE0, 8, 0, wc, lane);
    epilogue(acc, mpu_b + 4 * H, 0, nullptr, wr, wc, lane, Ch, Cl, Sh, Sl);
  } else {
    stage_row(E + (size_t)parents[2 * gr] * H, Sh, Sl, srow, q);       // k 0..127
    stage_row(E + (size_t)parents[2 * gr + 1] * H, Ch, Cl, srow, q);   // k 128..255
    load_w(w1, frags, SLOT_MPB0, 8, 0, wc, lane);
    __syncthreads();
    // L0 (K=256): mode0
    zero_acc(acc);
    gemm_mfma(acc, w1, Sh, Sl, wr, lane);
    load_w(w2, frags, SLOT_MPB0, 8, 4, wc, lane);
    gemm_mfma(acc, w2, Ch, Cl, wr, lane);
    __syncthreads();
    load_w(w1, frags, SLOT_MPB(0), 4, 0, wc, lane);
    epilogue(acc, mpb0_b, 0, nullptr, wr, wc, lane, Ch, Cl, Sh, Sl); __syncthreads();
    // L1: in C -> mode1
    zero_acc(acc); gemm_mfma(acc, w1, Ch, Cl, wr, lane); __syncthreads();
    load_w(w1, frags, SLOT_MPB(1), 4, 0, wc, lane);
    epilogue(acc, mpb_b, 1, nullptr, wr, wc, lane, Ch, Cl, Sh, Sl); __syncthreads();
    // L2: in S -> mode1
    zero_acc(acc); gemm_mfma(acc, w1, Sh, Sl, wr, lane); __syncthreads();
    load_w(w1, frags, SLOT_MPB(2), 4, 0, wc, lane);
    epilogue(acc, mpb_b + H, 1, nullptr, wr, wc, lane, Ch, Cl, Sh, Sl); __syncthreads();
    // L3: in S -> mode1
    zero_acc(acc); gemm_mfma(acc, w1, Sh, Sl, wr, lane); __syncthreads();
    load_w(w1, frags, SLOT_MPB(3), 4, 0, wc, lane);
    epilogue(acc, mpb_b + 2 * H, 1, nullptr, wr, wc, lane, Ch, Cl, Sh, Sl); __syncthreads();
    // L4: in S -> mode0 (C = redux result)
    zero_acc(acc); gemm_mfma(acc, w1, Sh, Sl, wr, lane); __syncthreads();
    load_w(w1, frags, SLOT_NE0, 8, 0, wc, lane);
    epilogue(acc, mpb_b + 3 * H, 0, nullptr, wr, wc, lane, Ch, Cl, Sh, Sl);
  }

  // ---- stage base rows into S planes (E rows for this layer still hold base) ----
  stage_row(E + (size_t)(s + row0 + srow) * H, Sh, Sl, srow, q);
  __syncthreads();

  // ---- node chain ----
  // L0 (K=256): [base|redux] -> mode0
  zero_acc(acc);
  gemm_mfma(acc, w1, Sh, Sl, wr, lane);
  load_w(w2, frags, SLOT_NE0, 8, 4, wc, lane);
  gemm_mfma(acc, w2, Ch, Cl, wr, lane);
  __syncthreads();
  load_w(w1, frags, SLOT_NE(0), 4, 0, wc, lane);
  epilogue(acc, ne0_b, 0, nullptr, wr, wc, lane, Ch, Cl, Sh, Sl); __syncthreads();
  // L1: in C -> mode1
  zero_acc(acc); gemm_mfma(acc, w1, Ch, Cl, wr, lane); __syncthreads();
  load_w(w1, frags, SLOT_NE(1), 4, 0, wc, lane);
  epilogue(acc, ne_b, 1, nullptr, wr, wc, lane, Ch, Cl, Sh, Sl); __syncthreads();
  // L2: in S -> mode1
  zero_acc(acc); gemm_mfma(acc, w1, Sh, Sl, wr, lane); __syncthreads();
  load_w(w1, frags, SLOT_NE(2), 4, 0, wc, lane);
  epilogue(acc, ne_b + H, 1, nullptr, wr, wc, lane, Ch, Cl, Sh, Sl); __syncthreads();
  // L3: in S -> mode1
  zero_acc(acc); gemm_mfma(acc, w1, Sh, Sl, wr, lane); __syncthreads();
  load_w(w1, frags, SLOT_NE(3), 4, 0, wc, lane);
  epilogue(acc, ne_b + 2 * H, 1, nullptr, wr, wc, lane, Ch, Cl, Sh, Sl); __syncthreads();
  // L4: in S -> global store
  zero_acc(acc); gemm_mfma(acc, w1, Sh, Sl, wr, lane);
  epilogue(acc, ne_b + 3 * H, 2, E + (size_t)(s + row0) * H, wr, wc, lane, Ch, Cl, Sh, Sl);
}

// ---------------------------------------------------------------------------
extern "C" void kernel_launch(void* const* d_in, const int* in_sizes, int n_in,
                              void* d_out, int out_size, void* d_ws, size_t ws_size,
                              hipStream_t stream) {
  const float* node_feats = (const float*)d_in[0];
  const float* emb_w  = (const float*)d_in[1];
  const float* emb_b  = (const float*)d_in[2];
  const float* ne0_w  = (const float*)d_in[3];
  const float* ne0_b  = (const float*)d_in[4];
  const float* ne_w   = (const float*)d_in[5];
  const float* ne_b   = (const float*)d_in[6];
  const float* mpu_w  = (const float*)d_in[7];
  const float* mpu_b  = (const float*)d_in[8];
  const float* mpb0_w = (const float*)d_in[9];
  const float* mpb0_b = (const float*)d_in[10];
  const float* mpb_w  = (const float*)d_in[11];
  const float* mpb_b  = (const float*)d_in[12];
  const int*   parents = (const int*)d_in[13];
  float* E = (float*)d_out;
  __bf16* frags = (__bf16*)d_ws;   // 544*2048 B ~= 1.1 MB

  prep_kernel<<<(TOTAL_FP + 3) / 4, 256, 0, stream>>>(frags, mpu_w, mpb0_w, mpb_w, ne0_w, ne_w);
  embed_kernel<<<N_TOTAL / 64, 256, 0, stream>>>(E, node_feats, emb_w, emb_b);
  for (int l = 1; l < L_LAYERS; ++l) {
    phase_kernel<<<M_NODES / 64, 256, 0, stream>>>(E, parents, frags, mpu_b, mpb0_b, mpb_b,
                                                   ne0_b, ne_b, l * M_NODES);
  }
}

// Round 3
// 1159.763 us; speedup vs baseline: 1.1133x; 1.1133x over previous
//
#include <hip/hip_runtime.h>
#include <hip/hip_bf16.h>

// ---------------------------------------------------------------------------
// GNN forward on MI355X, round 3.
// Round 1/2 were (by arithmetic) VGPR-spill-bound: whole-layer W fragments
// (128-256 VGPR) held live across barriers blew the 256-reg cap -> scratch.
// Round 3 streams W fragments per k-tile (2-deep register double buffer):
//   acc 32 + A-frags 64 + W 64 + misc ~ 190 VGPR -> no spill.
// Everything else (split bf16 hi/lo planes, XOR swizzle, swapped-operand
// MFMA, 64-row blocks, 2 blocks/CU) carried from the hardware-verified r2.
// ---------------------------------------------------------------------------

#define H        128
#define FEAT     32
#define M_NODES  32768
#define L_LAYERS 16
#define MU_      (M_NODES / 2)
#define N_TOTAL  (M_NODES * L_LAYERS)

typedef __bf16 bf16x8 __attribute__((ext_vector_type(8)));
typedef __bf16 bf16x4 __attribute__((ext_vector_type(4)));
typedef float  f32x4  __attribute__((ext_vector_type(4)));

// frag-pair slots in d_ws. One frag-pair = 2 KB = 1024 __bf16 (512 hi, 512 lo).
// frag-pair(ct,kt) lane l holds W[ct*16+(l&15)][kt*32+(l>>4)*8 + j], j=0..7.
#define SLOT_MPU(l) ((l) * 32)        // 5 layers, K=128 (8ct x 4kt)
#define SLOT_MPB0   160               // K=256 (8ct x 8kt)
#define SLOT_MPB(l) (224 + (l) * 32)  // 4 layers, K=128
#define SLOT_NE0    352               // K=256
#define SLOT_NE(l)  (416 + (l) * 32)  // 4 layers, K=128
#define TOTAL_FP    544

// LDS plane layout: [64 rows][128 cols] bf16, col-group (8 elems = 16 B)
// XOR-swizzled by row for bank-conflict-free row-wise b128 reads.
#define CG_SWZ(row, cg) ((cg) ^ ((row) & 7))

// ---------------------------------------------------------------------------
__global__ void prep_kernel(__bf16* __restrict__ frags,
                            const float* __restrict__ mpu_w,
                            const float* __restrict__ mpb0_w,
                            const float* __restrict__ mpb_w,
                            const float* __restrict__ ne0_w,
                            const float* __restrict__ ne_w) {
  int fp = blockIdx.x * 4 + (threadIdx.x >> 6);
  if (fp >= TOTAL_FP) return;
  int lane = threadIdx.x & 63;
  const float* src; int K; int idx;
  if (fp < 160)      { src = mpu_w + (fp >> 5) * H * H;         K = H;     idx = fp & 31; }
  else if (fp < 224) { src = mpb0_w;                            K = 2 * H; idx = fp - 160; }
  else if (fp < 352) { src = mpb_w + ((fp - 224) >> 5) * H * H; K = H;     idx = (fp - 224) & 31; }
  else if (fp < 416) { src = ne0_w;                             K = 2 * H; idx = fp - 352; }
  else               { src = ne_w + ((fp - 416) >> 5) * H * H;  K = H;     idx = (fp - 416) & 31; }
  int KT = K >> 5;
  int ct = idx / KT, kt = idx - ct * KT;
  int col = ct * 16 + (lane & 15);
  int k0  = kt * 32 + (lane >> 4) * 8;
  __bf16* dhi = frags + ((size_t)fp << 10) + lane * 8;
#pragma unroll
  for (int j = 0; j < 8; ++j) {
    float x  = src[col * K + k0 + j];
    __bf16 h = (__bf16)x;
    dhi[j]       = h;
    dhi[512 + j] = (__bf16)(x - (float)h);
  }
}

// ---------------------------------------------------------------------------
__global__ void embed_kernel(float* __restrict__ E,
                             const float* __restrict__ feats,
                             const float* __restrict__ emb_w,
                             const float* __restrict__ emb_b) {
  __shared__ float fl[64][36];
  int tid = threadIdx.x;
  size_t rbase = (size_t)blockIdx.x * 64;
  {
    int idx = tid;
#pragma unroll
    for (int rep = 0; rep < 2; ++rep, idx += 256) {
      int r = idx >> 3, c4 = idx & 7;
      *(f32x4*)&fl[r][c4 * 4] = *(const f32x4*)(feats + (rbase + r) * FEAT + c4 * 4);
    }
  }
  __syncthreads();
  int o = tid & 127, rh = tid >> 7;
  float w[32];
#pragma unroll
  for (int i = 0; i < 8; ++i) {
    f32x4 v = *(const f32x4*)(emb_w + o * FEAT + i * 4);
    w[i * 4 + 0] = v[0]; w[i * 4 + 1] = v[1]; w[i * 4 + 2] = v[2]; w[i * 4 + 3] = v[3];
  }
  float b = emb_b[o];
  for (int i = 0; i < 32; ++i) {
    int r = rh * 32 + i;
    float acc = b;
#pragma unroll
    for (int k4 = 0; k4 < 8; ++k4) {
      f32x4 f = *(const f32x4*)&fl[r][k4 * 4];
      acc += f[0] * w[k4 * 4] + f[1] * w[k4 * 4 + 1] + f[2] * w[k4 * 4 + 2] + f[3] * w[k4 * 4 + 3];
    }
    E[(rbase + r) * H + o] = fmaxf(acc, 0.f);
  }
}

// ---------------------------------------------------------------------------
struct Wkt { bf16x8 h[4]; bf16x8 l[4]; };  // one k-tile, 4 col-tiles: 32 VGPR

__device__ __forceinline__ void load_wkt(Wkt& w, const __bf16* __restrict__ frags,
                                         int slot, int KT, int kt, int wc, int lane) {
#pragma unroll
  for (int c = 0; c < 4; ++c) {
    const __bf16* fb =
        frags + (((size_t)(slot + (wc * 4 + c) * KT + kt)) << 10) + lane * 8;
    w.h[c] = *(const bf16x8*)fb;
    w.l[c] = *(const bf16x8*)(fb + 512);
  }
}

__device__ __forceinline__ void zero_acc(f32x4 (&acc)[2][4]) {
  f32x4 z = {0.f, 0.f, 0.f, 0.f};
#pragma unroll
  for (int i = 0; i < 2; ++i)
#pragma unroll
    for (int c = 0; c < 4; ++c) acc[i][c] = z;
}

// acc += split3( act[32 rows of wr] @ W^T ), one K=128 pass.
// W fragments streamed from L2 with a 2-deep register double buffer:
// kt+1's 8 loads are issued before kt's 24 MFMAs (counted-vmcnt overlap).
__device__ __forceinline__ void gemm(f32x4 (&acc)[2][4],
                                     const __bf16* Ph, const __bf16* Pl,
                                     const __bf16* __restrict__ frags, int slot, int KT,
                                     int ktoff, int wr, int wc, int lane) {
  int r16 = lane & 15, g = lane >> 4;
  Wkt w0, w1;
  load_wkt(w0, frags, slot, KT, ktoff, wc, lane);
  bf16x8 ah[2][4], al[2][4];
#pragma unroll
  for (int i = 0; i < 2; ++i) {
    int row = wr * 32 + i * 16 + r16;
#pragma unroll
    for (int kt = 0; kt < 4; ++kt) {
      int off = row * H + CG_SWZ(row, kt * 4 + g) * 8;
      ah[i][kt] = *(const bf16x8*)(Ph + off);
      al[i][kt] = *(const bf16x8*)(Pl + off);
    }
  }
#pragma unroll
  for (int kt = 0; kt < 4; ++kt) {
    Wkt& cur = (kt & 1) ? w1 : w0;
    Wkt& nxt = (kt & 1) ? w0 : w1;
    if (kt < 3) load_wkt(nxt, frags, slot, KT, ktoff + kt + 1, wc, lane);
    // 24 MFMAs, same-acc revisit distance 8
#pragma unroll
    for (int i = 0; i < 2; ++i)
#pragma unroll
      for (int c = 0; c < 4; ++c)
        acc[i][c] = __builtin_amdgcn_mfma_f32_16x16x32_bf16(cur.h[c], ah[i][kt], acc[i][c], 0, 0, 0);
#pragma unroll
    for (int i = 0; i < 2; ++i)
#pragma unroll
      for (int c = 0; c < 4; ++c)
        acc[i][c] = __builtin_amdgcn_mfma_f32_16x16x32_bf16(cur.l[c], ah[i][kt], acc[i][c], 0, 0, 0);
#pragma unroll
    for (int i = 0; i < 2; ++i)
#pragma unroll
      for (int c = 0; c < 4; ++c)
        acc[i][c] = __builtin_amdgcn_mfma_f32_16x16x32_bf16(cur.h[c], al[i][kt], acc[i][c], 0, 0, 0);
  }
}

// mode 0: C = relu(acc+b)
// mode 1: old = C; C = relu(acc+b); S = C + old
// mode 2: global fp32 store only
__device__ __forceinline__ void epilogue(const f32x4 (&acc)[2][4], const float* __restrict__ bias,
                                         int mode, float* __restrict__ eout, int wr, int wc,
                                         int lane, __bf16* Ch, __bf16* Cl, __bf16* Sh, __bf16* Sl) {
  int r16 = lane & 15, g = lane >> 4;
#pragma unroll
  for (int c = 0; c < 4; ++c) {
    int c0 = wc * 64 + c * 16 + g * 4;
    f32x4 bv = *(const f32x4*)(bias + c0);
#pragma unroll
    for (int i = 0; i < 2; ++i) {
      int row = wr * 32 + i * 16 + r16;
      f32x4 v;
#pragma unroll
      for (int j = 0; j < 4; ++j) v[j] = fmaxf(acc[i][c][j] + bv[j], 0.f);
      if (mode == 2) {
        *(f32x4*)(eout + (size_t)row * H + c0) = v;
      } else {
        int off = row * H + CG_SWZ(row, c0 >> 3) * 8 + (c0 & 7);
        if (mode == 1) {
          bf16x4 oh = *(bf16x4*)(Ch + off), ol = *(bf16x4*)(Cl + off);
          bf16x4 sh, sl;
#pragma unroll
          for (int j = 0; j < 4; ++j) {
            float sv = v[j] + (float)oh[j] + (float)ol[j];
            __bf16 t = (__bf16)sv;
            sh[j] = t; sl[j] = (__bf16)(sv - (float)t);
          }
          *(bf16x4*)(Sh + off) = sh; *(bf16x4*)(Sl + off) = sl;
        }
        bf16x4 h, l;
#pragma unroll
        for (int j = 0; j < 4; ++j) {
          __bf16 t = (__bf16)v[j];
          h[j] = t; l[j] = (__bf16)(v[j] - (float)t);
        }
        *(bf16x4*)(Ch + off) = h; *(bf16x4*)(Cl + off) = l;
      }
    }
  }
}

// thread covers floats [q*32, q*32+32) of `row`; splits into hi/lo planes.
__device__ __forceinline__ void stage_row(const float* __restrict__ src, __bf16* Ph, __bf16* Pl,
                                          int row, int q) {
#pragma unroll
  for (int i = 0; i < 4; ++i) {
    int cg = q * 4 + i;
    f32x4 f0 = *(const f32x4*)(src + cg * 8);
    f32x4 f1 = *(const f32x4*)(src + cg * 8 + 4);
    bf16x8 h, l;
#pragma unroll
    for (int j = 0; j < 4; ++j) {
      __bf16 t = (__bf16)f0[j]; h[j] = t; l[j] = (__bf16)(f0[j] - (float)t);
    }
#pragma unroll
    for (int j = 0; j < 4; ++j) {
      __bf16 t = (__bf16)f1[j]; h[4 + j] = t; l[4 + j] = (__bf16)(f1[j] - (float)t);
    }
    int off = row * H + CG_SWZ(row, cg) * 8;
    *(bf16x8*)(Ph + off) = h;
    *(bf16x8*)(Pl + off) = l;
  }
}

// ---------------------------------------------------------------------------
__global__ __launch_bounds__(256, 2) void phase_kernel(
    float* __restrict__ E, const int* __restrict__ parents, const __bf16* __restrict__ frags,
    const float* __restrict__ mpu_b, const float* __restrict__ mpb0_b,
    const float* __restrict__ mpb_b, const float* __restrict__ ne0_b,
    const float* __restrict__ ne_b, int s) {
  __shared__ __bf16 Ch[64 * H], Cl[64 * H], Sh[64 * H], Sl[64 * H];
  int t = blockIdx.x;
  bool un = t < (MU_ / 64);
  int row0 = t * 64;
  int tid = threadIdx.x;
  int lane = tid & 63, wave = tid >> 6;
  int wr = wave >> 1, wc = wave & 1;
  int srow = tid >> 2, q = tid & 3;
  int gr = s + row0 + srow;

  f32x4 acc[2][4];

  if (un) {
    stage_row(E + (size_t)parents[2 * gr] * H, Ch, Cl, srow, q);
    __syncthreads();
    // L0: in C -> mode0
    zero_acc(acc); gemm(acc, Ch, Cl, frags, SLOT_MPU(0), 4, 0, wr, wc, lane); __syncthreads();
    epilogue(acc, mpu_b, 0, nullptr, wr, wc, lane, Ch, Cl, Sh, Sl); __syncthreads();
    // L1: in C -> mode1 (C=a1, S=a0+a1)
    zero_acc(acc); gemm(acc, Ch, Cl, frags, SLOT_MPU(1), 4, 0, wr, wc, lane); __syncthreads();
    epilogue(acc, mpu_b + H, 1, nullptr, wr, wc, lane, Ch, Cl, Sh, Sl); __syncthreads();
    // L2: in S -> mode1
    zero_acc(acc); gemm(acc, Sh, Sl, frags, SLOT_MPU(2), 4, 0, wr, wc, lane); __syncthreads();
    epilogue(acc, mpu_b + 2 * H, 1, nullptr, wr, wc, lane, Ch, Cl, Sh, Sl); __syncthreads();
    // L3: in S -> mode1
    zero_acc(acc); gemm(acc, Sh, Sl, frags, SLOT_MPU(3), 4, 0, wr, wc, lane); __syncthreads();
    epilogue(acc, mpu_b + 3 * H, 1, nullptr, wr, wc, lane, Ch, Cl, Sh, Sl); __syncthreads();
    // L4: in S -> mode0 (C = redux result); stage base into S after the
    // post-gemm barrier (all S reads done; epilogue touches C only)
    zero_acc(acc); gemm(acc, Sh, Sl, frags, SLOT_MPU(4), 4, 0, wr, wc, lane); __syncthreads();
    epilogue(acc, mpu_b + 4 * H, 0, nullptr, wr, wc, lane, Ch, Cl, Sh, Sl);
  } else {
    stage_row(E + (size_t)parents[2 * gr] * H, Sh, Sl, srow, q);       // k 0..127
    stage_row(E + (size_t)parents[2 * gr + 1] * H, Ch, Cl, srow, q);   // k 128..255
    __syncthreads();
    // L0 (K=256): mode0
    zero_acc(acc);
    gemm(acc, Sh, Sl, frags, SLOT_MPB0, 8, 0, wr, wc, lane);
    gemm(acc, Ch, Cl, frags, SLOT_MPB0, 8, 4, wr, wc, lane);
    __syncthreads();
    epilogue(acc, mpb0_b, 0, nullptr, wr, wc, lane, Ch, Cl, Sh, Sl); __syncthreads();
    // L1: in C -> mode1
    zero_acc(acc); gemm(acc, Ch, Cl, frags, SLOT_MPB(0), 4, 0, wr, wc, lane); __syncthreads();
    epilogue(acc, mpb_b, 1, nullptr, wr, wc, lane, Ch, Cl, Sh, Sl); __syncthreads();
    // L2: in S -> mode1
    zero_acc(acc); gemm(acc, Sh, Sl, frags, SLOT_MPB(1), 4, 0, wr, wc, lane); __syncthreads();
    epilogue(acc, mpb_b + H, 1, nullptr, wr, wc, lane, Ch, Cl, Sh, Sl); __syncthreads();
    // L3: in S -> mode1
    zero_acc(acc); gemm(acc, Sh, Sl, frags, SLOT_MPB(2), 4, 0, wr, wc, lane); __syncthreads();
    epilogue(acc, mpb_b + 2 * H, 1, nullptr, wr, wc, lane, Ch, Cl, Sh, Sl); __syncthreads();
    // L4: in S -> mode0
    zero_acc(acc); gemm(acc, Sh, Sl, frags, SLOT_MPB(3), 4, 0, wr, wc, lane); __syncthreads();
    epilogue(acc, mpb_b + 3 * H, 0, nullptr, wr, wc, lane, Ch, Cl, Sh, Sl);
  }

  // stage base rows into S planes (E rows for this layer still hold base).
  // Safe: last gemm's S reads completed before the preceding barrier; the
  // L4 epilogue wrote C planes only.
  stage_row(E + (size_t)(s + row0 + srow) * H, Sh, Sl, srow, q);
  __syncthreads();

  // ---- node chain ----
  // L0 (K=256): [base|redux] -> mode0
  zero_acc(acc);
  gemm(acc, Sh, Sl, frags, SLOT_NE0, 8, 0, wr, wc, lane);
  gemm(acc, Ch, Cl, frags, SLOT_NE0, 8, 4, wr, wc, lane);
  __syncthreads();
  epilogue(acc, ne0_b, 0, nullptr, wr, wc, lane, Ch, Cl, Sh, Sl); __syncthreads();
  // L1: in C -> mode1
  zero_acc(acc); gemm(acc, Ch, Cl, frags, SLOT_NE(0), 4, 0, wr, wc, lane); __syncthreads();
  epilogue(acc, ne_b, 1, nullptr, wr, wc, lane, Ch, Cl, Sh, Sl); __syncthreads();
  // L2: in S -> mode1
  zero_acc(acc); gemm(acc, Sh, Sl, frags, SLOT_NE(1), 4, 0, wr, wc, lane); __syncthreads();
  epilogue(acc, ne_b + H, 1, nullptr, wr, wc, lane, Ch, Cl, Sh, Sl); __syncthreads();
  // L3: in S -> mode1
  zero_acc(acc); gemm(acc, Sh, Sl, frags, SLOT_NE(2), 4, 0, wr, wc, lane); __syncthreads();
  epilogue(acc, ne_b + 2 * H, 1, nullptr, wr, wc, lane, Ch, Cl, Sh, Sl); __syncthreads();
  // L4: in S -> global store (no LDS access in epilogue mode 2)
  zero_acc(acc); gemm(acc, Sh, Sl, frags, SLOT_NE(3), 4, 0, wr, wc, lane);
  epilogue(acc, ne_b + 3 * H, 2, E + (size_t)(s + row0) * H, wr, wc, lane, Ch, Cl, Sh, Sl);
}

// ---------------------------------------------------------------------------
extern "C" void kernel_launch(void* const* d_in, const int* in_sizes, int n_in,
                              void* d_out, int out_size, void* d_ws, size_t ws_size,
                              hipStream_t stream) {
  const float* node_feats = (const float*)d_in[0];
  const float* emb_w  = (const float*)d_in[1];
  const float* emb_b  = (const float*)d_in[2];
  const float* ne0_w  = (const float*)d_in[3];
  const float* ne0_b  = (const float*)d_in[4];
  const float* ne_w   = (const float*)d_in[5];
  const float* ne_b   = (const float*)d_in[6];
  const float* mpu_w  = (const float*)d_in[7];
  const float* mpu_b  = (const float*)d_in[8];
  const float* mpb0_w = (const float*)d_in[9];
  const float* mpb0_b = (const float*)d_in[10];
  const float* mpb_w  = (const float*)d_in[11];
  const float* mpb_b  = (const float*)d_in[12];
  const int*   parents = (const int*)d_in[13];
  float* E = (float*)d_out;
  __bf16* frags = (__bf16*)d_ws;   // 544*2048 B ~= 1.1 MB

  prep_kernel<<<(TOTAL_FP + 3) / 4, 256, 0, stream>>>(frags, mpu_w, mpb0_w, mpb_w, ne0_w, ne_w);
  embed_kernel<<<N_TOTAL / 64, 256, 0, stream>>>(E, node_feats, emb_w, emb_b);
  for (int l = 1; l < L_LAYERS; ++l) {
    phase_kernel<<<M_NODES / 64, 256, 0, stream>>>(E, parents, frags, mpu_b, mpb0_b, mpb_b,
                                                   ne0_b, ne_b, l * M_NODES);
  }
}